// Round 1
// baseline (87.840 us; speedup 1.0000x reference)
//
#include <hip/hip_runtime.h>
#include <stdint.h>

#define MM   256
#define NN   256
#define DIMD 512
#define ROWS (MM * NN)

// ---------------------------------------------------------------------------
// Kernel 1: BMU search. One wave (64 lanes) per row; each lane handles 8
// consecutive floats (2x float4). Squared L2 distance (argmin-equivalent to
// the reference's norm). Pack (dist_bits << 32) | row into uint64 so that
// atomicMin yields min distance with smallest-index tie-break, exactly the
// jnp.argmin semantics (distances are >= 0 so float bits are order-preserving
// as uint32).
// ---------------------------------------------------------------------------
__global__ __launch_bounds__(256) void som_argmin_kernel(
    const float* __restrict__ x,
    const float* __restrict__ w,
    unsigned long long* __restrict__ best)
{
    const int lane  = threadIdx.x & 63;
    const int wave  = threadIdx.x >> 6;
    const int gwave = blockIdx.x * 4 + wave;
    const int nwav  = gridDim.x * 4;

    // x fragment for this lane: elements [lane*8, lane*8+8)
    const float4* x4 = reinterpret_cast<const float4*>(x) + lane * 2;
    const float4 xa = x4[0];
    const float4 xb = x4[1];

    unsigned long long local_best = ~0ull;

    for (int row = gwave; row < ROWS; row += nwav) {
        const float4* w4 =
            reinterpret_cast<const float4*>(w + (size_t)row * DIMD) + lane * 2;
        const float4 wa = w4[0];
        const float4 wb = w4[1];

        float d = 0.0f, t;
        t = wa.x - xa.x; d = fmaf(t, t, d);
        t = wa.y - xa.y; d = fmaf(t, t, d);
        t = wa.z - xa.z; d = fmaf(t, t, d);
        t = wa.w - xa.w; d = fmaf(t, t, d);
        t = wb.x - xb.x; d = fmaf(t, t, d);
        t = wb.y - xb.y; d = fmaf(t, t, d);
        t = wb.z - xb.z; d = fmaf(t, t, d);
        t = wb.w - xb.w; d = fmaf(t, t, d);

        // butterfly reduce across the 64-lane wave (all lanes get the sum)
        #pragma unroll
        for (int off = 32; off > 0; off >>= 1)
            d += __shfl_xor(d, off, 64);

        unsigned long long key =
            (((unsigned long long)__float_as_uint(d)) << 32) |
            (unsigned long long)(unsigned)row;
        local_best = (key < local_best) ? key : local_best;
    }

    __shared__ unsigned long long sbest[4];
    if (lane == 0) sbest[wave] = local_best;
    __syncthreads();
    if (threadIdx.x == 0) {
        unsigned long long b = sbest[0];
        #pragma unroll
        for (int i = 1; i < 4; ++i) b = (sbest[i] < b) ? sbest[i] : b;
        atomicMin(best, b);
    }
}

// ---------------------------------------------------------------------------
// Kernel 2: weight update + winner extraction. One wave per row. Reads the
// BMU key produced by kernel 1, computes the Gaussian neighbourhood factor
// once per row (lane-uniform), then does the vectorized fused update.
// Winner = OLD weights[bmu] (read happens before the write; output buffer is
// disjoint from the input weights, so no aliasing).
// ---------------------------------------------------------------------------
__global__ __launch_bounds__(256) void som_update_kernel(
    const float* __restrict__ x,
    const float* __restrict__ w,
    const int* __restrict__ it_ptr,
    const unsigned long long* __restrict__ best,
    float* __restrict__ out)
{
    const int lane  = threadIdx.x & 63;
    const int wave  = threadIdx.x >> 6;
    const int gwave = blockIdx.x * 4 + wave;
    const int nwav  = gridDim.x * 4;

    const unsigned bmu = (unsigned)(*best & 0xFFFFFFFFull);
    const float bi = (float)(bmu >> 8);    // bmu / N
    const float bj = (float)(bmu & 255u);  // bmu % N

    // Match Python double-precision scalar math, then drop to f32 coefs.
    const double itd      = (double)(*it_ptr);
    const double lr       = 1.0 - itd / 1000.0;
    const float  alpha_op = (float)(0.3 * lr);
    const double sigma_op = 128.0 * lr;   // SIGMA = max(M,N)/2 = 128
    const float  inv_s2   = (float)(1.0 / (sigma_op * sigma_op));

    const float4* x4 = reinterpret_cast<const float4*>(x) + lane * 2;
    const float4 xa = x4[0];
    const float4 xb = x4[1];

    float* winner      = out;         // first 512 floats
    float* new_weights = out + DIMD;  // then 65536 x 512

    for (int row = gwave; row < ROWS; row += nwav) {
        const float di = (float)(row >> 8) - bi;
        const float dj = (float)(row & 255) - bj;
        const float d2 = di * di + dj * dj;
        const float coef = alpha_op * expf(-d2 * inv_s2);

        const float4* w4 =
            reinterpret_cast<const float4*>(w + (size_t)row * DIMD) + lane * 2;
        const float4 wa = w4[0];
        const float4 wb = w4[1];

        float4 oa, ob;
        oa.x = fmaf(coef, xa.x - wa.x, wa.x);
        oa.y = fmaf(coef, xa.y - wa.y, wa.y);
        oa.z = fmaf(coef, xa.z - wa.z, wa.z);
        oa.w = fmaf(coef, xa.w - wa.w, wa.w);
        ob.x = fmaf(coef, xb.x - wb.x, wb.x);
        ob.y = fmaf(coef, xb.y - wb.y, wb.y);
        ob.z = fmaf(coef, xb.z - wb.z, wb.z);
        ob.w = fmaf(coef, xb.w - wb.w, wb.w);

        float4* o4 =
            reinterpret_cast<float4*>(new_weights + (size_t)row * DIMD) + lane * 2;
        o4[0] = oa;
        o4[1] = ob;

        if (row == (int)bmu) {
            float4* wn = reinterpret_cast<float4*>(winner) + lane * 2;
            wn[0] = wa;   // OLD weights row
            wn[1] = wb;
        }
    }
}

extern "C" void kernel_launch(void* const* d_in, const int* in_sizes, int n_in,
                              void* d_out, int out_size, void* d_ws, size_t ws_size,
                              hipStream_t stream) {
    const float* x       = (const float*)d_in[0];
    const float* weights = (const float*)d_in[1];
    // d_in[2] = y (unused by the math)
    const int*   it_ptr  = (const int*)d_in[3];

    float* out = (float*)d_out;
    unsigned long long* best = (unsigned long long*)d_ws;

    // Re-initialize the argmin cell every call (graph-capture-safe memset).
    hipMemsetAsync(best, 0xFF, sizeof(unsigned long long), stream);

    const int blocks = 2048;  // 4 waves/block, grid-stride over 65536 rows
    som_argmin_kernel<<<blocks, 256, 0, stream>>>(x, weights, best);
    som_update_kernel<<<blocks, 256, 0, stream>>>(x, weights, it_ptr, best, out);
}

// Round 3
// 70.631 us; speedup vs baseline: 1.2436x; 1.2436x over previous
//
#include <hip/hip_runtime.h>
#include <stdint.h>

#define MM   256
#define NN   256
#define DIMD 512
#define ROWS (MM * NN)

#define K1_BLOCKS 2048
#define WPB       4              // waves per block
#define ROWS_PER_WAVE 8          // 2048 blocks * 4 waves * 8 rows = 65536

// native clang vector type — accepted by __builtin_nontemporal_store
typedef float vfloat4 __attribute__((ext_vector_type(4)));

// ---------------------------------------------------------------------------
// Kernel 1: BMU search. One wave per 8-row strip, fully unrolled so the 8
// distance reductions are INDEPENDENT shfl chains (ILP-pipelined, not 8
// serial 6-deep latency chains). Lane reads float4 chunks (lane) and
// (lane+64) -> each load instruction covers a dense contiguous 1024 B.
// Key = (dist_bits << 32) | row: min-key == min distance, first-index
// tie-break (distances >= 0 so float bits are order-preserving).
// Block result is plain-stored to slots[blockIdx.x] -- no init, no atomics.
// ---------------------------------------------------------------------------
__global__ __launch_bounds__(256) void som_argmin_kernel(
    const float* __restrict__ x,
    const float* __restrict__ w,
    unsigned long long* __restrict__ slots)
{
    const int lane  = threadIdx.x & 63;
    const int wave  = threadIdx.x >> 6;
    const int gwave = blockIdx.x * WPB + wave;
    const int row0  = gwave * ROWS_PER_WAVE;

    const float4* x4 = reinterpret_cast<const float4*>(x);
    const float4 xa = x4[lane];
    const float4 xb = x4[lane + 64];

    float d[ROWS_PER_WAVE];

    #pragma unroll
    for (int r = 0; r < ROWS_PER_WAVE; ++r) {
        const float4* w4 =
            reinterpret_cast<const float4*>(w + (size_t)(row0 + r) * DIMD);
        const float4 wa = w4[lane];
        const float4 wb = w4[lane + 64];

        float s = 0.0f, t;
        t = wa.x - xa.x; s = fmaf(t, t, s);
        t = wa.y - xa.y; s = fmaf(t, t, s);
        t = wa.z - xa.z; s = fmaf(t, t, s);
        t = wa.w - xa.w; s = fmaf(t, t, s);
        t = wb.x - xb.x; s = fmaf(t, t, s);
        t = wb.y - xb.y; s = fmaf(t, t, s);
        t = wb.z - xb.z; s = fmaf(t, t, s);
        t = wb.w - xb.w; s = fmaf(t, t, s);
        d[r] = s;
    }

    // 8 independent butterfly reductions (chains overlap; DS pipe throughput-
    // bound, not latency-bound).
    #pragma unroll
    for (int off = 32; off > 0; off >>= 1) {
        #pragma unroll
        for (int r = 0; r < ROWS_PER_WAVE; ++r)
            d[r] += __shfl_xor(d[r], off, 64);
    }

    unsigned long long best = ~0ull;
    #pragma unroll
    for (int r = 0; r < ROWS_PER_WAVE; ++r) {
        unsigned long long key =
            (((unsigned long long)__float_as_uint(d[r])) << 32) |
            (unsigned long long)(unsigned)(row0 + r);
        best = (key < best) ? key : best;
    }

    __shared__ unsigned long long sbest[WPB];
    if (lane == 0) sbest[wave] = best;
    __syncthreads();
    if (threadIdx.x == 0) {
        unsigned long long b = sbest[0];
        #pragma unroll
        for (int i = 1; i < WPB; ++i) b = (sbest[i] < b) ? sbest[i] : b;
        slots[blockIdx.x] = b;
    }
}

// ---------------------------------------------------------------------------
// Kernel 2: slot-reduce (2048 x 8 B, L2-hot) -> bmu broadcast -> streaming
// fused update with NONTEMPORAL stores (don't evict the 134 MB weights from
// Infinity Cache; output is never re-read by us). Winner = OLD weights[bmu].
// ---------------------------------------------------------------------------
__global__ __launch_bounds__(256) void som_update_kernel(
    const float* __restrict__ x,
    const float* __restrict__ w,
    const int* __restrict__ it_ptr,
    const unsigned long long* __restrict__ slots,
    float* __restrict__ out)
{
    const int lane  = threadIdx.x & 63;
    const int wave  = threadIdx.x >> 6;

    // ---- reduce the 2048 per-block candidates, broadcast bmu ----
    unsigned long long b = ~0ull;
    for (int i = threadIdx.x; i < K1_BLOCKS; i += 256) {
        unsigned long long v = slots[i];
        b = (v < b) ? v : b;
    }
    #pragma unroll
    for (int off = 32; off > 0; off >>= 1) {
        unsigned long long o = __shfl_xor(b, off, 64);
        b = (o < b) ? o : b;
    }
    __shared__ unsigned long long sbest[WPB];
    if (lane == 0) sbest[wave] = b;
    __syncthreads();
    unsigned long long g = sbest[0];
    #pragma unroll
    for (int i = 1; i < WPB; ++i) g = (sbest[i] < g) ? sbest[i] : g;

    const unsigned bmu = (unsigned)(g & 0xFFFFFFFFull);
    const float bi = (float)(bmu >> 8);
    const float bj = (float)(bmu & 255u);

    // scalar decay math in double, matching Python semantics
    const double itd      = (double)(*it_ptr);
    const double lr       = 1.0 - itd / 1000.0;
    const float  alpha_op = (float)(0.3 * lr);
    const double sigma_op = 128.0 * lr;           // SIGMA = max(M,N)/2
    const float  inv_s2   = (float)(1.0 / (sigma_op * sigma_op));

    const float4* x4 = reinterpret_cast<const float4*>(x);
    const float4 xa = x4[lane];
    const float4 xb = x4[lane + 64];

    float* winner      = out;          // first 512 floats
    float* new_weights = out + DIMD;   // then 65536 x 512

    const int gwave = blockIdx.x * WPB + wave;
    const int row0  = gwave * ROWS_PER_WAVE;

    #pragma unroll
    for (int r = 0; r < ROWS_PER_WAVE; ++r) {
        const int row = row0 + r;
        const float di = (float)(row >> 8) - bi;
        const float dj = (float)(row & 255) - bj;
        const float d2 = di * di + dj * dj;
        const float coef = alpha_op * __expf(-d2 * inv_s2);

        const float4* w4 =
            reinterpret_cast<const float4*>(w + (size_t)row * DIMD);
        const float4 wa = w4[lane];
        const float4 wb = w4[lane + 64];

        vfloat4 oa, ob;
        oa.x = fmaf(coef, xa.x - wa.x, wa.x);
        oa.y = fmaf(coef, xa.y - wa.y, wa.y);
        oa.z = fmaf(coef, xa.z - wa.z, wa.z);
        oa.w = fmaf(coef, xa.w - wa.w, wa.w);
        ob.x = fmaf(coef, xb.x - wb.x, wb.x);
        ob.y = fmaf(coef, xb.y - wb.y, wb.y);
        ob.z = fmaf(coef, xb.z - wb.z, wb.z);
        ob.w = fmaf(coef, xb.w - wb.w, wb.w);

        vfloat4* o4 = reinterpret_cast<vfloat4*>(new_weights + (size_t)row * DIMD);
        __builtin_nontemporal_store(oa, o4 + lane);
        __builtin_nontemporal_store(ob, o4 + lane + 64);

        if (row == (int)bmu) {
            float4* wn = reinterpret_cast<float4*>(winner);
            wn[lane]      = wa;   // OLD weights row
            wn[lane + 64] = wb;
        }
    }
}

extern "C" void kernel_launch(void* const* d_in, const int* in_sizes, int n_in,
                              void* d_out, int out_size, void* d_ws, size_t ws_size,
                              hipStream_t stream) {
    const float* x       = (const float*)d_in[0];
    const float* weights = (const float*)d_in[1];
    // d_in[2] = y (unused by the math)
    const int*   it_ptr  = (const int*)d_in[3];

    float* out = (float*)d_out;
    unsigned long long* slots = (unsigned long long*)d_ws;  // 2048 * 8 B

    som_argmin_kernel<<<K1_BLOCKS, 256, 0, stream>>>(x, weights, slots);
    som_update_kernel<<<K1_BLOCKS, 256, 0, stream>>>(x, weights, it_ptr, slots, out);
}